// Round 1
// baseline (2350.040 us; speedup 1.0000x reference)
//
#include <hip/hip_runtime.h>
#include <hip/hip_bf16.h>
#include <math.h>

// Problem dims (fixed by reference)
#define BB 32
#define LL 12
#define NN 4096
#define CIN 4
#define HID 64
#define GRID_F 8
#define NSTEP 10
#define DTS 0.1f
#define BLN (BB*LL)          // 384 rows (b*L+l)
#define ELEMS (BB*LL*NN)     // 1572864

// ---------------------------------------------------------------------------
// Kernel 1: base_pred[b,l,n] = prior + tanh(adapter)*kasa_gate
// ---------------------------------------------------------------------------
__global__ __launch_bounds__(256) void base_pred_kernel(
    const float* __restrict__ hd,   // [B][L][N][4]
    const float* __restrict__ Wk,   // [12][12]
    const float* __restrict__ bk,   // [12]
    const float* __restrict__ Wad,  // [12][12]
    const float* __restrict__ bad,  // [12]
    const float* __restrict__ kgp,  // scalar
    float* __restrict__ base)       // [384][4096]
{
    int idx = blockIdx.x * 256 + threadIdx.x;     // 0 .. 131071  (b,n)
    int b = idx >> 12;
    int n = idx & 4095;
    const float* hb = hd + (size_t)b * (LL * NN * CIN) + (size_t)n * CIN;

    float h0[12];
    float prior = 0.f;
#pragma unroll
    for (int t = 0; t < 12; ++t) {
        float4 v = *reinterpret_cast<const float4*>(hb + (size_t)t * (NN * CIN));
        h0[t] = v.x;                  // channel 0
        if (t == 11) prior = v.w;     // channel 3, last step
    }
    float kgate = kgp[0];

    float kr[12];
#pragma unroll
    for (int l = 0; l < 12; ++l) {
        float p = bk[l];
#pragma unroll
        for (int t = 0; t < 12; ++t) p = fmaf(h0[t], Wk[l * 12 + t], p);
        kr[l] = p;
    }
#pragma unroll
    for (int o = 0; o < 12; ++o) {
        float p = bad[o];
#pragma unroll
        for (int l = 0; l < 12; ++l) p = fmaf(kr[l], Wad[o * 12 + l], p);
        base[((size_t)(b * 12 + o)) * NN + n] = prior + tanhf(p) * kgate;
    }
}

// ---------------------------------------------------------------------------
// Kernel 2: tconst[k][h] = b1[h] + sum_g cos(t_k*(g+1))*A1[h][2][g]
//                                 + sin(t_k*(g+1))*B1[h][2][g]
// ---------------------------------------------------------------------------
__global__ void tconst_kernel(const float* __restrict__ A1,
                              const float* __restrict__ B1,
                              const float* __restrict__ b1,
                              float* __restrict__ tc)  // [10][64]
{
    int idx = blockIdx.x * blockDim.x + threadIdx.x;
    if (idx >= NSTEP * HID) return;
    int k = idx >> 6, h = idx & 63;
    float t = DTS * (float)k;
    float p = b1[h];
#pragma unroll
    for (int g = 0; g < GRID_F; ++g) {
        float ang = t * (float)(g + 1);
        p += cosf(ang) * A1[(h * 3 + 2) * 8 + g] + sinf(ang) * B1[(h * 3 + 2) * 8 + g];
    }
    tc[idx] = p;
}

// ---------------------------------------------------------------------------
// Tiled f32 GEMM:  C[row][m] = alpha * sum_n X[row][n] * U(n,m)   (+ C0)
//   UT=true : U accessed as U[n][m]   (cond_spec = U^T base / 64)
//   UT=false: U accessed as U[m][n]   (gen residual)
// Tiles: 64(rows) x 64(m), BK=32, 256 threads, 4x4 per thread.
// ---------------------------------------------------------------------------
#define GMT 64
#define GNT 64
#define GKT 32
#define GPAD 4

template <bool UT>
__global__ __launch_bounds__(256) void gemm_u(
    const float* __restrict__ X,    // [384][4096]
    const float* __restrict__ Uq,   // [4096][4096]
    const float* __restrict__ C0,   // nullable [384][4096]
    float* __restrict__ C,          // [384][4096]
    const float* __restrict__ alpha_ptr,  // nullable device scalar
    float alpha_const)
{
    __shared__ float Xs[GKT][GMT + GPAD];
    __shared__ float Us[GKT][GNT + GPAD];

    const int t = threadIdx.x;
    const int m0 = blockIdx.y * GMT;   // row (b*L+l) offset
    const int n0 = blockIdx.x * GNT;   // m offset
    const int tx = t & 15;
    const int ty = t >> 4;

    // staging mapping: 64 rows x 32 cols, thread reads 8 contiguous floats
    const int srow = t >> 2;
    const int scol = (t & 3) * 8;

    float acc[4][4] = {};

    for (int k0 = 0; k0 < NN; k0 += GKT) {
        // ---- stage X tile (transposed into Xs[k][row]) ----
        {
            const float4* xp = reinterpret_cast<const float4*>(
                &X[(size_t)(m0 + srow) * NN + k0 + scol]);
            float4 a = xp[0], b4 = xp[1];
            Xs[scol + 0][srow] = a.x;  Xs[scol + 1][srow] = a.y;
            Xs[scol + 2][srow] = a.z;  Xs[scol + 3][srow] = a.w;
            Xs[scol + 4][srow] = b4.x; Xs[scol + 5][srow] = b4.y;
            Xs[scol + 6][srow] = b4.z; Xs[scol + 7][srow] = b4.w;
        }
        // ---- stage U tile ----
        if (UT) {
            // Us[kk][j] = U[(k0+kk)][n0+j] ; direct (coalesced along j)
            int kk = t >> 3;
            int j0 = (t & 7) * 8;
            const float4* up = reinterpret_cast<const float4*>(
                &Uq[(size_t)(k0 + kk) * NN + n0 + j0]);
            float4 a = up[0], b4 = up[1];
            Us[kk][j0 + 0] = a.x;  Us[kk][j0 + 1] = a.y;
            Us[kk][j0 + 2] = a.z;  Us[kk][j0 + 3] = a.w;
            Us[kk][j0 + 4] = b4.x; Us[kk][j0 + 5] = b4.y;
            Us[kk][j0 + 6] = b4.z; Us[kk][j0 + 7] = b4.w;
        } else {
            // Us[kk][j] = U[(n0+j)][k0+kk] ; read along kk (coalesced), store transposed
            const float4* up = reinterpret_cast<const float4*>(
                &Uq[(size_t)(n0 + srow) * NN + k0 + scol]);
            float4 a = up[0], b4 = up[1];
            Us[scol + 0][srow] = a.x;  Us[scol + 1][srow] = a.y;
            Us[scol + 2][srow] = a.z;  Us[scol + 3][srow] = a.w;
            Us[scol + 4][srow] = b4.x; Us[scol + 5][srow] = b4.y;
            Us[scol + 6][srow] = b4.z; Us[scol + 7][srow] = b4.w;
        }
        __syncthreads();

#pragma unroll
        for (int kk = 0; kk < GKT; ++kk) {
            float a[4], bb[4];
#pragma unroll
            for (int i = 0; i < 4; ++i) a[i] = Xs[kk][ty * 4 + i];
#pragma unroll
            for (int j = 0; j < 4; ++j) bb[j] = Us[kk][tx * 4 + j];
#pragma unroll
            for (int i = 0; i < 4; ++i)
#pragma unroll
                for (int j = 0; j < 4; ++j)
                    acc[i][j] = fmaf(a[i], bb[j], acc[i][j]);
        }
        __syncthreads();
    }

    float alpha = alpha_const;
    if (alpha_ptr) alpha *= alpha_ptr[0];

#pragma unroll
    for (int i = 0; i < 4; ++i) {
        int row = m0 + ty * 4 + i;
        size_t off = (size_t)row * NN + n0 + tx * 4;
        float4 v;
        v.x = acc[i][0] * alpha;
        v.y = acc[i][1] * alpha;
        v.z = acc[i][2] * alpha;
        v.w = acc[i][3] * alpha;
        if (C0) {
            float4 c0 = *reinterpret_cast<const float4*>(&C0[off]);
            v.x += c0.x; v.y += c0.y; v.z += c0.z; v.w += c0.w;
        }
        *reinterpret_cast<float4*>(&C[off]) = v;
    }
}

// ---------------------------------------------------------------------------
// Kernel 3: fused Euler ODE. One thread per element.
//  - cond-channel contribution precomputed per element (step-invariant)
//  - t-channel contribution from tconst (uniform, scalar-cached)
//  - x-channel: sincos + harmonic recurrence, 64x16 matvec per step
//  Reads cond from xc[i], writes x_final back to xc[i] (in place).
// ---------------------------------------------------------------------------
__global__ __launch_bounds__(256) void ode_kernel(
    const float* __restrict__ x0,
    float* xc,                           // in: cond_spec, out: x_final
    const float* __restrict__ tc,        // [10][64] (incl b1)
    const float* __restrict__ A1,        // [64][3][8]
    const float* __restrict__ B1,
    const float* __restrict__ W2,        // [64]
    const float* __restrict__ b2)        // [1]
{
    int i = blockIdx.x * 256 + threadIdx.x;   // exactly ELEMS threads
    float x = x0[i];
    float cnd = xc[i];

    // harmonics of cond
    float cs, cc;
    __sincosf(cnd, &cs, &cc);
    float cg[8], sg[8];
    cg[0] = cc; sg[0] = cs;
#pragma unroll
    for (int g = 1; g < 8; ++g) {
        cg[g] = cg[g - 1] * cc - sg[g - 1] * cs;
        sg[g] = sg[g - 1] * cc + cg[g - 1] * cs;
    }

    // step-invariant cond contribution per hidden unit (registers)
    float ccond[HID];
#pragma unroll
    for (int h = 0; h < HID; ++h) {
        float p = 0.f;
#pragma unroll
        for (int g = 0; g < 8; ++g) {
            p = fmaf(cg[g], A1[(h * 3 + 1) * 8 + g], p);
            p = fmaf(sg[g], B1[(h * 3 + 1) * 8 + g], p);
        }
        ccond[h] = p;
    }

    float b2v = b2[0];

#pragma unroll 1
    for (int k = 0; k < NSTEP; ++k) {
        float xs, xcv;
        __sincosf(x, &xs, &xcv);
        float cgx[8], sgx[8];
        cgx[0] = xcv; sgx[0] = xs;
#pragma unroll
        for (int g = 1; g < 8; ++g) {
            cgx[g] = cgx[g - 1] * xcv - sgx[g - 1] * xs;
            sgx[g] = sgx[g - 1] * xcv + cgx[g - 1] * xs;
        }
        float acc = 0.f;
#pragma unroll
        for (int h = 0; h < HID; ++h) {
            float pre = tc[k * HID + h] + ccond[h];
#pragma unroll
            for (int g = 0; g < 8; ++g) {
                pre = fmaf(cgx[g], A1[h * 24 + g], pre);
                pre = fmaf(sgx[g], B1[h * 24 + g], pre);
            }
            float sl = pre / (1.f + __expf(-pre));   // silu
            acc = fmaf(sl, W2[h], acc);
        }
        x = fmaf(DTS, acc + b2v, x);
    }
    xc[i] = x;   // x_final (scale folded into final GEMM alpha)
}

// ---------------------------------------------------------------------------
extern "C" void kernel_launch(void* const* d_in, const int* in_sizes, int n_in,
                              void* d_out, int out_size, void* d_ws, size_t ws_size,
                              hipStream_t stream) {
    const float* hd  = (const float*)d_in[0];
    const float* x0  = (const float*)d_in[1];
    const float* U   = (const float*)d_in[2];
    const float* Wk  = (const float*)d_in[3];
    const float* bk  = (const float*)d_in[4];
    const float* Wad = (const float*)d_in[5];
    const float* bad = (const float*)d_in[6];
    const float* kg  = (const float*)d_in[7];
    const float* fg  = (const float*)d_in[8];
    const float* A1  = (const float*)d_in[9];
    const float* B1  = (const float*)d_in[10];
    const float* b1  = (const float*)d_in[11];
    const float* W2  = (const float*)d_in[12];
    const float* b2  = (const float*)d_in[13];
    float* out = (float*)d_out;

    float* ws   = (float*)d_ws;
    float* base = ws;                    // [384][4096]
    float* xc   = ws + (size_t)ELEMS;    // cond_spec, then x_final (in place)
    float* tc   = ws + (size_t)2 * ELEMS;// [640]

    // 1) base_pred
    base_pred_kernel<<<(BB * NN) / 256, 256, 0, stream>>>(hd, Wk, bk, Wad, bad, kg, base);
    // 2) time-channel constants
    tconst_kernel<<<3, 256, 0, stream>>>(A1, B1, b1, tc);
    // 3) cond_spec = U^T base / 64
    gemm_u<true><<<dim3(NN / GNT, BLN / GMT), 256, 0, stream>>>(
        base, U, nullptr, xc, nullptr, 1.0f / 64.0f);
    // 4) Euler ODE (in-place cond -> x_final)
    ode_kernel<<<ELEMS / 256, 256, 0, stream>>>(x0, xc, tc, A1, B1, W2, b2);
    // 5) out = base + fm_gate * 64 * (U @ x_final)
    gemm_u<false><<<dim3(NN / GNT, BLN / GMT), 256, 0, stream>>>(
        xc, U, base, out, fg, 64.0f);
}

// Round 2
// 2156.351 us; speedup vs baseline: 1.0898x; 1.0898x over previous
//
#include <hip/hip_runtime.h>
#include <hip/hip_bf16.h>
#include <math.h>

// Problem dims (fixed by reference)
#define BB 32
#define LL 12
#define NN 4096
#define CIN 4
#define HID 64
#define GRID_F 8
#define NSTEP 10
#define DTS 0.1f
#define BLN (BB*LL)          // 384 rows (b*L+l)
#define ELEMS (BB*LL*NN)     // 1572864

// ---------------------------------------------------------------------------
// Kernel 1: base_pred[b,l,n] = prior + tanh(adapter)*kasa_gate
// ---------------------------------------------------------------------------
__global__ __launch_bounds__(256) void base_pred_kernel(
    const float* __restrict__ hd,   // [B][L][N][4]
    const float* __restrict__ Wk,   // [12][12]
    const float* __restrict__ bk,   // [12]
    const float* __restrict__ Wad,  // [12][12]
    const float* __restrict__ bad,  // [12]
    const float* __restrict__ kgp,  // scalar
    float* __restrict__ base)       // [384][4096]
{
    int idx = blockIdx.x * 256 + threadIdx.x;     // 0 .. 131071  (b,n)
    int b = idx >> 12;
    int n = idx & 4095;
    const float* hb = hd + (size_t)b * (LL * NN * CIN) + (size_t)n * CIN;

    float h0[12];
    float prior = 0.f;
#pragma unroll
    for (int t = 0; t < 12; ++t) {
        float4 v = *reinterpret_cast<const float4*>(hb + (size_t)t * (NN * CIN));
        h0[t] = v.x;                  // channel 0
        if (t == 11) prior = v.w;     // channel 3, last step
    }
    float kgate = kgp[0];

    float kr[12];
#pragma unroll
    for (int l = 0; l < 12; ++l) {
        float p = bk[l];
#pragma unroll
        for (int t = 0; t < 12; ++t) p = fmaf(h0[t], Wk[l * 12 + t], p);
        kr[l] = p;
    }
#pragma unroll
    for (int o = 0; o < 12; ++o) {
        float p = bad[o];
#pragma unroll
        for (int l = 0; l < 12; ++l) p = fmaf(kr[l], Wad[o * 12 + l], p);
        base[((size_t)(b * 12 + o)) * NN + n] = prior + tanhf(p) * kgate;
    }
}

// ---------------------------------------------------------------------------
// Kernel 2: tconst[k][h] = b1[h] + sum_g cos(t_k*(g+1))*A1[h][2][g]
//                                 + sin(t_k*(g+1))*B1[h][2][g]
// ---------------------------------------------------------------------------
__global__ void tconst_kernel(const float* __restrict__ A1,
                              const float* __restrict__ B1,
                              const float* __restrict__ b1,
                              float* __restrict__ tc)  // [10][64]
{
    int idx = blockIdx.x * blockDim.x + threadIdx.x;
    if (idx >= NSTEP * HID) return;
    int k = idx >> 6, h = idx & 63;
    float t = DTS * (float)k;
    float p = b1[h];
#pragma unroll
    for (int g = 0; g < GRID_F; ++g) {
        float ang = t * (float)(g + 1);
        p += cosf(ang) * A1[(h * 3 + 2) * 8 + g] + sinf(ang) * B1[(h * 3 + 2) * 8 + g];
    }
    tc[idx] = p;
}

// ---------------------------------------------------------------------------
// Tiled f32 GEMM:  C[row][m] = alpha * sum_n X[row][n] * U(n,m)   (+ C0)
// ---------------------------------------------------------------------------
#define GMT 64
#define GNT 64
#define GKT 32
#define GPAD 4

template <bool UT>
__global__ __launch_bounds__(256) void gemm_u(
    const float* __restrict__ X,    // [384][4096]
    const float* __restrict__ Uq,   // [4096][4096]
    const float* __restrict__ C0,   // nullable [384][4096]
    float* __restrict__ C,          // [384][4096]
    const float* __restrict__ alpha_ptr,  // nullable device scalar
    float alpha_const)
{
    __shared__ float Xs[GKT][GMT + GPAD];
    __shared__ float Us[GKT][GNT + GPAD];

    const int t = threadIdx.x;
    const int m0 = blockIdx.y * GMT;
    const int n0 = blockIdx.x * GNT;
    const int tx = t & 15;
    const int ty = t >> 4;

    const int srow = t >> 2;
    const int scol = (t & 3) * 8;

    float acc[4][4] = {};

    for (int k0 = 0; k0 < NN; k0 += GKT) {
        {
            const float4* xp = reinterpret_cast<const float4*>(
                &X[(size_t)(m0 + srow) * NN + k0 + scol]);
            float4 a = xp[0], b4 = xp[1];
            Xs[scol + 0][srow] = a.x;  Xs[scol + 1][srow] = a.y;
            Xs[scol + 2][srow] = a.z;  Xs[scol + 3][srow] = a.w;
            Xs[scol + 4][srow] = b4.x; Xs[scol + 5][srow] = b4.y;
            Xs[scol + 6][srow] = b4.z; Xs[scol + 7][srow] = b4.w;
        }
        if (UT) {
            int kk = t >> 3;
            int j0 = (t & 7) * 8;
            const float4* up = reinterpret_cast<const float4*>(
                &Uq[(size_t)(k0 + kk) * NN + n0 + j0]);
            float4 a = up[0], b4 = up[1];
            Us[kk][j0 + 0] = a.x;  Us[kk][j0 + 1] = a.y;
            Us[kk][j0 + 2] = a.z;  Us[kk][j0 + 3] = a.w;
            Us[kk][j0 + 4] = b4.x; Us[kk][j0 + 5] = b4.y;
            Us[kk][j0 + 6] = b4.z; Us[kk][j0 + 7] = b4.w;
        } else {
            const float4* up = reinterpret_cast<const float4*>(
                &Uq[(size_t)(n0 + srow) * NN + k0 + scol]);
            float4 a = up[0], b4 = up[1];
            Us[scol + 0][srow] = a.x;  Us[scol + 1][srow] = a.y;
            Us[scol + 2][srow] = a.z;  Us[scol + 3][srow] = a.w;
            Us[scol + 4][srow] = b4.x; Us[scol + 5][srow] = b4.y;
            Us[scol + 6][srow] = b4.z; Us[scol + 7][srow] = b4.w;
        }
        __syncthreads();

#pragma unroll
        for (int kk = 0; kk < GKT; ++kk) {
            float a[4], bb[4];
#pragma unroll
            for (int i = 0; i < 4; ++i) a[i] = Xs[kk][ty * 4 + i];
#pragma unroll
            for (int j = 0; j < 4; ++j) bb[j] = Us[kk][tx * 4 + j];
#pragma unroll
            for (int i = 0; i < 4; ++i)
#pragma unroll
                for (int j = 0; j < 4; ++j)
                    acc[i][j] = fmaf(a[i], bb[j], acc[i][j]);
        }
        __syncthreads();
    }

    float alpha = alpha_const;
    if (alpha_ptr) alpha *= alpha_ptr[0];

#pragma unroll
    for (int i = 0; i < 4; ++i) {
        int row = m0 + ty * 4 + i;
        size_t off = (size_t)row * NN + n0 + tx * 4;
        float4 v;
        v.x = acc[i][0] * alpha;
        v.y = acc[i][1] * alpha;
        v.z = acc[i][2] * alpha;
        v.w = acc[i][3] * alpha;
        if (C0) {
            float4 c0 = *reinterpret_cast<const float4*>(&C0[off]);
            v.x += c0.x; v.y += c0.y; v.z += c0.z; v.w += c0.w;
        }
        *reinterpret_cast<float4*>(&C[off]) = v;
    }
}

// ---------------------------------------------------------------------------
// Kernel 3: fused Euler ODE.  (v2: no register spill, fast silu)
//  - ccond (step-invariant cond contribution) packed as 32 VGPRs of 2xbf16
//  - silu via v_rcp_f32 instead of precise division
// ---------------------------------------------------------------------------
__device__ __forceinline__ unsigned pack2bf(float a, float b) {
    // a -> high 16 bits, b -> low 16 bits (both RNE-rounded bf16)
    unsigned ua = __float_as_uint(a);
    unsigned ub = __float_as_uint(b);
    ua += 0x7FFFu + ((ua >> 16) & 1u);
    ub += 0x7FFFu + ((ub >> 16) & 1u);
    return (ua & 0xFFFF0000u) | (ub >> 16);
}

__global__ __launch_bounds__(256) void ode_kernel(
    const float* __restrict__ x0,
    float* xc,                           // in: cond_spec, out: x_final
    const float* __restrict__ tc,        // [10][64] (incl b1)
    const float* __restrict__ A1,        // [64][3][8]
    const float* __restrict__ B1,
    const float* __restrict__ W2,        // [64]
    const float* __restrict__ b2)        // [1]
{
    int i = blockIdx.x * 256 + threadIdx.x;   // exactly ELEMS threads
    float x = x0[i];
    float cnd = xc[i];

    // harmonics of cond
    float cs, cc;
    __sincosf(cnd, &cs, &cc);
    float cg[8], sg[8];
    cg[0] = cc; sg[0] = cs;
#pragma unroll
    for (int g = 1; g < 8; ++g) {
        cg[g] = cg[g - 1] * cc - sg[g - 1] * cs;
        sg[g] = sg[g - 1] * cc + cg[g - 1] * cs;
    }

    // step-invariant cond contribution, packed 2 x bf16 per VGPR (32 regs)
    unsigned ccp[HID / 2];
#pragma unroll
    for (int hp = 0; hp < HID / 2; ++hp) {
        int h0 = 2 * hp, h1 = 2 * hp + 1;
        float p0 = 0.f, p1 = 0.f;
#pragma unroll
        for (int g = 0; g < 8; ++g) {
            p0 = fmaf(cg[g], A1[(h0 * 3 + 1) * 8 + g], p0);
            p0 = fmaf(sg[g], B1[(h0 * 3 + 1) * 8 + g], p0);
            p1 = fmaf(cg[g], A1[(h1 * 3 + 1) * 8 + g], p1);
            p1 = fmaf(sg[g], B1[(h1 * 3 + 1) * 8 + g], p1);
        }
        ccp[hp] = pack2bf(p0, p1);
    }

    const float b2v = b2[0];

#pragma unroll 1
    for (int k = 0; k < NSTEP; ++k) {
        float xs, xcv;
        __sincosf(x, &xs, &xcv);
        float cgx[8], sgx[8];
        cgx[0] = xcv; sgx[0] = xs;
#pragma unroll
        for (int g = 1; g < 8; ++g) {
            cgx[g] = cgx[g - 1] * xcv - sgx[g - 1] * xs;
            sgx[g] = sgx[g - 1] * xcv + cgx[g - 1] * xs;
        }
        float acc = b2v;
#pragma unroll
        for (int hp = 0; hp < HID / 2; ++hp) {
            const int h0 = 2 * hp, h1 = 2 * hp + 1;
            unsigned u = ccp[hp];
            float pre0 = tc[k * HID + h0] + __uint_as_float(u & 0xFFFF0000u);
            float pre1 = tc[k * HID + h1] + __uint_as_float(u << 16);
#pragma unroll
            for (int g = 0; g < 8; ++g) {
                pre0 = fmaf(cgx[g], A1[h0 * 24 + g], pre0);
                pre0 = fmaf(sgx[g], B1[h0 * 24 + g], pre0);
                pre1 = fmaf(cgx[g], A1[h1 * 24 + g], pre1);
                pre1 = fmaf(sgx[g], B1[h1 * 24 + g], pre1);
            }
            // fast silu: x * 1/(1+e^-x) with v_rcp
            float sl0 = pre0 * __builtin_amdgcn_rcpf(1.f + __expf(-pre0));
            float sl1 = pre1 * __builtin_amdgcn_rcpf(1.f + __expf(-pre1));
            acc = fmaf(sl0, W2[h0], acc);
            acc = fmaf(sl1, W2[h1], acc);
        }
        x = fmaf(DTS, acc, x);
    }
    xc[i] = x;   // x_final (scale folded into final GEMM alpha)
}

// ---------------------------------------------------------------------------
extern "C" void kernel_launch(void* const* d_in, const int* in_sizes, int n_in,
                              void* d_out, int out_size, void* d_ws, size_t ws_size,
                              hipStream_t stream) {
    const float* hd  = (const float*)d_in[0];
    const float* x0  = (const float*)d_in[1];
    const float* U   = (const float*)d_in[2];
    const float* Wk  = (const float*)d_in[3];
    const float* bk  = (const float*)d_in[4];
    const float* Wad = (const float*)d_in[5];
    const float* bad = (const float*)d_in[6];
    const float* kg  = (const float*)d_in[7];
    const float* fg  = (const float*)d_in[8];
    const float* A1  = (const float*)d_in[9];
    const float* B1  = (const float*)d_in[10];
    const float* b1  = (const float*)d_in[11];
    const float* W2  = (const float*)d_in[12];
    const float* b2  = (const float*)d_in[13];
    float* out = (float*)d_out;

    float* ws   = (float*)d_ws;
    float* base = ws;                    // [384][4096]
    float* xc   = ws + (size_t)ELEMS;    // cond_spec, then x_final (in place)
    float* tc   = ws + (size_t)2 * ELEMS;// [640]

    // 1) base_pred
    base_pred_kernel<<<(BB * NN) / 256, 256, 0, stream>>>(hd, Wk, bk, Wad, bad, kg, base);
    // 2) time-channel constants
    tconst_kernel<<<3, 256, 0, stream>>>(A1, B1, b1, tc);
    // 3) cond_spec = U^T base / 64
    gemm_u<true><<<dim3(NN / GNT, BLN / GMT), 256, 0, stream>>>(
        base, U, nullptr, xc, nullptr, 1.0f / 64.0f);
    // 4) Euler ODE (in-place cond -> x_final)
    ode_kernel<<<ELEMS / 256, 256, 0, stream>>>(x0, xc, tc, A1, B1, W2, b2);
    // 5) out = base + fm_gate * 64 * (U @ x_final)
    gemm_u<false><<<dim3(NN / GNT, BLN / GMT), 256, 0, stream>>>(
        xc, U, base, out, fg, 64.0f);
}

// Round 3
// 890.490 us; speedup vs baseline: 2.6390x; 2.4215x over previous
//
#include <hip/hip_runtime.h>
#include <hip/hip_bf16.h>
#include <math.h>

// Problem dims (fixed by reference)
#define BB 32
#define LL 12
#define NN 4096
#define CIN 4
#define HID 64
#define GRID_F 8
#define NSTEP 10
#define DTS 0.1f
#define BLN (BB*LL)          // 384 rows (b*L+l)
#define ELEMS (BB*LL*NN)     // 1572864

#define L2E 1.4426950408889634f
#define LN2 0.6931471805599453f

typedef __attribute__((ext_vector_type(8))) short short8;
typedef __attribute__((ext_vector_type(16))) float f32x16;

union FragU { unsigned u[4]; uint4 v; short8 s; };

__device__ __forceinline__ unsigned pack2bf(float a, float b) {
    // a -> high 16 bits, b -> low 16 bits (both RNE-rounded bf16)
    unsigned ua = __float_as_uint(a);
    unsigned ub = __float_as_uint(b);
    ua += 0x7FFFu + ((ua >> 16) & 1u);
    ub += 0x7FFFu + ((ub >> 16) & 1u);
    return (ua & 0xFFFF0000u) | (ub >> 16);
}

// ---------------------------------------------------------------------------
// Kernel 1: base_pred[b,l,n] = prior + tanh(adapter)*kasa_gate
// ---------------------------------------------------------------------------
__global__ __launch_bounds__(256) void base_pred_kernel(
    const float* __restrict__ hd,   // [B][L][N][4]
    const float* __restrict__ Wk,   // [12][12]
    const float* __restrict__ bk,   // [12]
    const float* __restrict__ Wad,  // [12][12]
    const float* __restrict__ bad,  // [12]
    const float* __restrict__ kgp,  // scalar
    float* __restrict__ base)       // [384][4096]
{
    int idx = blockIdx.x * 256 + threadIdx.x;     // 0 .. 131071  (b,n)
    int b = idx >> 12;
    int n = idx & 4095;
    const float* hb = hd + (size_t)b * (LL * NN * CIN) + (size_t)n * CIN;

    float h0[12];
    float prior = 0.f;
#pragma unroll
    for (int t = 0; t < 12; ++t) {
        float4 v = *reinterpret_cast<const float4*>(hb + (size_t)t * (NN * CIN));
        h0[t] = v.x;                  // channel 0
        if (t == 11) prior = v.w;     // channel 3, last step
    }
    float kgate = kgp[0];

    float kr[12];
#pragma unroll
    for (int l = 0; l < 12; ++l) {
        float p = bk[l];
#pragma unroll
        for (int t = 0; t < 12; ++t) p = fmaf(h0[t], Wk[l * 12 + t], p);
        kr[l] = p;
    }
#pragma unroll
    for (int o = 0; o < 12; ++o) {
        float p = bad[o];
#pragma unroll
        for (int l = 0; l < 12; ++l) p = fmaf(kr[l], Wad[o * 12 + l], p);
        base[((size_t)(b * 12 + o)) * NN + n] = prior + tanhf(p) * kgate;
    }
}

// ---------------------------------------------------------------------------
// Kernel 2: t-feature table, bf16, MFMA-B-frag layout:
//   tf16[k*16 + hi*8 + j] = (hi==0 ? cos((j+1)*t_k) : sin((j+1)*t_k))
// ---------------------------------------------------------------------------
__global__ void tfeat_kernel(unsigned short* __restrict__ tf16)
{
    int idx = blockIdx.x * blockDim.x + threadIdx.x;
    if (idx >= NSTEP * 16) return;
    int k = idx >> 4;
    int r = idx & 15;
    int hi = r >> 3;
    int j = r & 7;
    float ang = DTS * (float)k * (float)(j + 1);
    float v = hi ? sinf(ang) : cosf(ang);
    unsigned uv = __float_as_uint(v);
    uv += 0x7FFFu + ((uv >> 16) & 1u);
    tf16[idx] = (unsigned short)(uv >> 16);
}

// ---------------------------------------------------------------------------
// Tiled f32 GEMM:  C[row][m] = alpha * sum_n X[row][n] * U(n,m)   (+ C0)
// ---------------------------------------------------------------------------
#define GMT 64
#define GNT 64
#define GKT 32
#define GPAD 4

template <bool UT>
__global__ __launch_bounds__(256) void gemm_u(
    const float* __restrict__ X,    // [384][4096]
    const float* __restrict__ Uq,   // [4096][4096]
    const float* __restrict__ C0,   // nullable [384][4096]
    float* __restrict__ C,          // [384][4096]
    const float* __restrict__ alpha_ptr,  // nullable device scalar
    float alpha_const)
{
    __shared__ float Xs[GKT][GMT + GPAD];
    __shared__ float Us[GKT][GNT + GPAD];

    const int t = threadIdx.x;
    const int m0 = blockIdx.y * GMT;
    const int n0 = blockIdx.x * GNT;
    const int tx = t & 15;
    const int ty = t >> 4;

    const int srow = t >> 2;
    const int scol = (t & 3) * 8;

    float acc[4][4] = {};

    for (int k0 = 0; k0 < NN; k0 += GKT) {
        {
            const float4* xp = reinterpret_cast<const float4*>(
                &X[(size_t)(m0 + srow) * NN + k0 + scol]);
            float4 a = xp[0], b4 = xp[1];
            Xs[scol + 0][srow] = a.x;  Xs[scol + 1][srow] = a.y;
            Xs[scol + 2][srow] = a.z;  Xs[scol + 3][srow] = a.w;
            Xs[scol + 4][srow] = b4.x; Xs[scol + 5][srow] = b4.y;
            Xs[scol + 6][srow] = b4.z; Xs[scol + 7][srow] = b4.w;
        }
        if (UT) {
            int kk = t >> 3;
            int j0 = (t & 7) * 8;
            const float4* up = reinterpret_cast<const float4*>(
                &Uq[(size_t)(k0 + kk) * NN + n0 + j0]);
            float4 a = up[0], b4 = up[1];
            Us[kk][j0 + 0] = a.x;  Us[kk][j0 + 1] = a.y;
            Us[kk][j0 + 2] = a.z;  Us[kk][j0 + 3] = a.w;
            Us[kk][j0 + 4] = b4.x; Us[kk][j0 + 5] = b4.y;
            Us[kk][j0 + 6] = b4.z; Us[kk][j0 + 7] = b4.w;
        } else {
            const float4* up = reinterpret_cast<const float4*>(
                &Uq[(size_t)(n0 + srow) * NN + k0 + scol]);
            float4 a = up[0], b4 = up[1];
            Us[scol + 0][srow] = a.x;  Us[scol + 1][srow] = a.y;
            Us[scol + 2][srow] = a.z;  Us[scol + 3][srow] = a.w;
            Us[scol + 4][srow] = b4.x; Us[scol + 5][srow] = b4.y;
            Us[scol + 6][srow] = b4.z; Us[scol + 7][srow] = b4.w;
        }
        __syncthreads();

#pragma unroll
        for (int kk = 0; kk < GKT; ++kk) {
            float a[4], bb[4];
#pragma unroll
            for (int i = 0; i < 4; ++i) a[i] = Xs[kk][ty * 4 + i];
#pragma unroll
            for (int j = 0; j < 4; ++j) bb[j] = Us[kk][tx * 4 + j];
#pragma unroll
            for (int i = 0; i < 4; ++i)
#pragma unroll
                for (int j = 0; j < 4; ++j)
                    acc[i][j] = fmaf(a[i], bb[j], acc[i][j]);
        }
        __syncthreads();
    }

    float alpha = alpha_const;
    if (alpha_ptr) alpha *= alpha_ptr[0];

#pragma unroll
    for (int i = 0; i < 4; ++i) {
        int row = m0 + ty * 4 + i;
        size_t off = (size_t)row * NN + n0 + tx * 4;
        float4 v;
        v.x = acc[i][0] * alpha;
        v.y = acc[i][1] * alpha;
        v.z = acc[i][2] * alpha;
        v.w = acc[i][3] * alpha;
        if (C0) {
            float4 c0 = *reinterpret_cast<const float4*>(&C0[off]);
            v.x += c0.x; v.y += c0.y; v.z += c0.z; v.w += c0.w;
        }
        *reinterpret_cast<float4*>(&C[off]) = v;
    }
}

// ---------------------------------------------------------------------------
// Kernel 3: fused Euler ODE via MFMA.
//  Per wave: 32 elements. D[h=64(M), elem=32(N)] built by 6x mfma 32x32x16:
//   K-chunks: x-features / cond-features / t-features (each 8 cos + 8 sin).
//  Weights (A1,B1 all channels) live in 24 VGPRs of bf16 A-frags, loaded once.
//  b1 is the MFMA C-init. exp2-trick: all pre-weights scaled by log2e,
//  W2 scaled by ln2, so silu(p) = q*rcp(1+exp2(-q)) with q = p*log2e.
// ---------------------------------------------------------------------------
__global__ __launch_bounds__(256) void ode_kernel(
    const float* __restrict__ x0,
    float* __restrict__ xc,                    // in: cond_spec, out: x_final
    const unsigned short* __restrict__ tf16,   // [10][16] bf16 t-features
    const float* __restrict__ A1,              // [64][3][8]
    const float* __restrict__ B1,
    const float* __restrict__ b1,              // [64]
    const float* __restrict__ W2,              // [64]
    const float* __restrict__ b2)              // [1]
{
    const int tid  = threadIdx.x;
    const int lane = tid & 63;
    const int e31  = lane & 31;
    const int hi   = lane >> 5;
    const int wv   = tid >> 6;
    const size_t eg = (size_t)blockIdx.x * 128 + (size_t)wv * 32 + e31;

    // ---- weight A-fragments (persistent), scaled by log2(e) ----
    // A[m=h(l&31)][k=hi*8+j]; hi=0 rows of K carry cos-weights (A1),
    // hi=1 rows carry sin-weights (B1). Chunk c = input channel (x,cond,t).
    FragU af[2][3];
#pragma unroll
    for (int mt = 0; mt < 2; ++mt) {
        int h = mt * 32 + e31;
#pragma unroll
        for (int c = 0; c < 3; ++c) {
            const float* wp = (hi ? B1 : A1) + (size_t)(h * 3 + c) * 8;
            float4 f0 = *reinterpret_cast<const float4*>(wp);
            float4 f1 = *reinterpret_cast<const float4*>(wp + 4);
            af[mt][c].u[0] = pack2bf(f0.y * L2E, f0.x * L2E);
            af[mt][c].u[1] = pack2bf(f0.w * L2E, f0.z * L2E);
            af[mt][c].u[2] = pack2bf(f1.y * L2E, f1.x * L2E);
            af[mt][c].u[3] = pack2bf(f1.w * L2E, f1.z * L2E);
        }
    }

    // ---- C-init (b1*log2e) and W2*ln2, indexed by this lane's D-rows ----
    f32x16 ci0, ci1;
    float w2v0[16], w2v1[16];
#pragma unroll
    for (int r = 0; r < 16; ++r) {
        int row = (r & 3) + 8 * (r >> 2) + 4 * hi;   // verified C/D row map
        ci0[r] = b1[row] * L2E;
        ci1[r] = b1[32 + row] * L2E;
        w2v0[r] = W2[row] * LN2;
        w2v1[r] = W2[32 + row] * LN2;
    }

    float x   = x0[eg];
    float cnd = xc[eg];
    const float db2 = DTS * b2[0];

    // ---- cond-channel B-fragment (step-invariant) ----
    FragU bc;
    {
        float s, c;
        __sincosf(cnd, &s, &c);
        float cg[8], sg[8];
        cg[0] = c; sg[0] = s;
#pragma unroll
        for (int g = 1; g < 8; ++g) {
            cg[g] = cg[g - 1] * c - sg[g - 1] * s;
            sg[g] = sg[g - 1] * c + cg[g - 1] * s;
        }
#pragma unroll
        for (int t = 0; t < 4; ++t) {
            float a0 = hi ? sg[2 * t]     : cg[2 * t];
            float a1 = hi ? sg[2 * t + 1] : cg[2 * t + 1];
            bc.u[t] = pack2bf(a1, a0);
        }
    }

    // ---- t-feature fragment, prefetch k=0 ----
    FragU bt;
    bt.v = *reinterpret_cast<const uint4*>(tf16 + hi * 8);

#pragma unroll 1
    for (int k = 0; k < NSTEP; ++k) {
        // x-features
        float s, c;
        __sincosf(x, &s, &c);
        float cg[8], sg[8];
        cg[0] = c; sg[0] = s;
#pragma unroll
        for (int g = 1; g < 8; ++g) {
            cg[g] = cg[g - 1] * c - sg[g - 1] * s;
            sg[g] = sg[g - 1] * c + cg[g - 1] * s;
        }
        FragU bx;
#pragma unroll
        for (int t = 0; t < 4; ++t) {
            float a0 = hi ? sg[2 * t]     : cg[2 * t];
            float a1 = hi ? sg[2 * t + 1] : cg[2 * t + 1];
            bx.u[t] = pack2bf(a1, a0);
        }

        // prefetch next step's t-fragment
        FragU btn;
        int kn = (k + 1 < NSTEP) ? (k + 1) : (NSTEP - 1);
        btn.v = *reinterpret_cast<const uint4*>(tf16 + kn * 16 + hi * 8);

        f32x16 a0 = __builtin_amdgcn_mfma_f32_32x32x16_bf16(af[0][0].s, bx.s, ci0, 0, 0, 0);
        f32x16 a1v = __builtin_amdgcn_mfma_f32_32x32x16_bf16(af[1][0].s, bx.s, ci1, 0, 0, 0);
        a0  = __builtin_amdgcn_mfma_f32_32x32x16_bf16(af[0][1].s, bc.s, a0, 0, 0, 0);
        a1v = __builtin_amdgcn_mfma_f32_32x32x16_bf16(af[1][1].s, bc.s, a1v, 0, 0, 0);
        a0  = __builtin_amdgcn_mfma_f32_32x32x16_bf16(af[0][2].s, bt.s, a0, 0, 0, 0);
        a1v = __builtin_amdgcn_mfma_f32_32x32x16_bf16(af[1][2].s, bt.s, a1v, 0, 0, 0);

        // silu + W2 dot (exp2-trick), per-lane 32 h-values of element e31
        float dot = 0.f;
#pragma unroll
        for (int r = 0; r < 16; ++r) {
            float q = a0[r];
            float sgm = __builtin_amdgcn_rcpf(1.f + exp2f(-q));
            dot = fmaf(q * sgm, w2v0[r], dot);
        }
#pragma unroll
        for (int r = 0; r < 16; ++r) {
            float q = a1v[r];
            float sgm = __builtin_amdgcn_rcpf(1.f + exp2f(-q));
            dot = fmaf(q * sgm, w2v1[r], dot);
        }
        float other = __shfl_xor(dot, 32, 64);   // cross-half h-reduction
        dot += other;
        x = fmaf(DTS, dot, x) + db2;
        bt = btn;
    }

    if (!hi) xc[eg] = x;   // one lane per element writes x_final
}

// ---------------------------------------------------------------------------
extern "C" void kernel_launch(void* const* d_in, const int* in_sizes, int n_in,
                              void* d_out, int out_size, void* d_ws, size_t ws_size,
                              hipStream_t stream) {
    const float* hd  = (const float*)d_in[0];
    const float* x0  = (const float*)d_in[1];
    const float* U   = (const float*)d_in[2];
    const float* Wk  = (const float*)d_in[3];
    const float* bk  = (const float*)d_in[4];
    const float* Wad = (const float*)d_in[5];
    const float* bad = (const float*)d_in[6];
    const float* kg  = (const float*)d_in[7];
    const float* fg  = (const float*)d_in[8];
    const float* A1  = (const float*)d_in[9];
    const float* B1  = (const float*)d_in[10];
    const float* b1  = (const float*)d_in[11];
    const float* W2  = (const float*)d_in[12];
    const float* b2  = (const float*)d_in[13];
    float* out = (float*)d_out;

    float* ws   = (float*)d_ws;
    float* base = ws;                    // [384][4096]
    float* xc   = ws + (size_t)ELEMS;    // cond_spec, then x_final (in place)
    unsigned short* tf16 = (unsigned short*)(ws + (size_t)2 * ELEMS); // [10][16]

    // 1) base_pred
    base_pred_kernel<<<(BB * NN) / 256, 256, 0, stream>>>(hd, Wk, bk, Wad, bad, kg, base);
    // 2) t-feature table (bf16, B-frag layout)
    tfeat_kernel<<<1, 256, 0, stream>>>(tf16);
    // 3) cond_spec = U^T base / 64
    gemm_u<true><<<dim3(NN / GNT, BLN / GMT), 256, 0, stream>>>(
        base, U, nullptr, xc, nullptr, 1.0f / 64.0f);
    // 4) Euler ODE (in-place cond -> x_final), 128 elems / 256-thread block
    ode_kernel<<<ELEMS / 128, 256, 0, stream>>>(x0, xc, tf16, A1, B1, b1, W2, b2);
    // 5) out = base + fm_gate * 64 * (U @ x_final)
    gemm_u<false><<<dim3(NN / GNT, BLN / GMT), 256, 0, stream>>>(
        xc, U, base, out, fg, 64.0f);
}

// Round 4
// 661.462 us; speedup vs baseline: 3.5528x; 1.3462x over previous
//
#include <hip/hip_runtime.h>
#include <hip/hip_bf16.h>
#include <math.h>

// Problem dims (fixed by reference)
#define BB 32
#define LL 12
#define NN 4096
#define CIN 4
#define HID 64
#define GRID_F 8
#define NSTEP 10
#define DTS 0.1f
#define BLN (BB*LL)          // 384 rows (b*L+l)
#define ELEMS (BB*LL*NN)     // 1572864
#define K4 4096

#define L2E 1.4426950408889634f
#define LN2 0.6931471805599453f

typedef __attribute__((ext_vector_type(8))) short short8;
typedef __attribute__((ext_vector_type(16))) float f32x16;

union FragU { unsigned u[4]; uint4 v; short8 s; };

__device__ __forceinline__ unsigned pack2bf(float a, float b) {
    // a -> high 16 bits, b -> low 16 bits (both RNE-rounded bf16)
    unsigned ua = __float_as_uint(a);
    unsigned ub = __float_as_uint(b);
    ua += 0x7FFFu + ((ua >> 16) & 1u);
    ub += 0x7FFFu + ((ub >> 16) & 1u);
    return (ua & 0xFFFF0000u) | (ub >> 16);
}

__device__ __forceinline__ unsigned short bf16of(float a) {
    unsigned ua = __float_as_uint(a);
    ua += 0x7FFFu + ((ua >> 16) & 1u);
    return (unsigned short)(ua >> 16);
}

__device__ __forceinline__ f32x16 fzero16() {
    f32x16 z;
#pragma unroll
    for (int i = 0; i < 16; ++i) z[i] = 0.f;
    return z;
}

// ---------------------------------------------------------------------------
// Kernel 1: base_pred[b,l,n] = prior + tanh(adapter)*kasa_gate  (f32 + bf16)
// ---------------------------------------------------------------------------
__global__ __launch_bounds__(256) void base_pred_kernel(
    const float* __restrict__ hd,   // [B][L][N][4]
    const float* __restrict__ Wk,   // [12][12]
    const float* __restrict__ bk,   // [12]
    const float* __restrict__ Wad,  // [12][12]
    const float* __restrict__ bad,  // [12]
    const float* __restrict__ kgp,  // scalar
    float* __restrict__ base,       // [384][4096]
    unsigned short* __restrict__ base16)  // nullable [384][4096] bf16
{
    int idx = blockIdx.x * 256 + threadIdx.x;     // 0 .. 131071  (b,n)
    int b = idx >> 12;
    int n = idx & 4095;
    const float* hb = hd + (size_t)b * (LL * NN * CIN) + (size_t)n * CIN;

    float h0[12];
    float prior = 0.f;
#pragma unroll
    for (int t = 0; t < 12; ++t) {
        float4 v = *reinterpret_cast<const float4*>(hb + (size_t)t * (NN * CIN));
        h0[t] = v.x;
        if (t == 11) prior = v.w;
    }
    float kgate = kgp[0];

    float kr[12];
#pragma unroll
    for (int l = 0; l < 12; ++l) {
        float p = bk[l];
#pragma unroll
        for (int t = 0; t < 12; ++t) p = fmaf(h0[t], Wk[l * 12 + t], p);
        kr[l] = p;
    }
#pragma unroll
    for (int o = 0; o < 12; ++o) {
        float p = bad[o];
#pragma unroll
        for (int l = 0; l < 12; ++l) p = fmaf(kr[l], Wad[o * 12 + l], p);
        float val = prior + tanhf(p) * kgate;
        size_t off = ((size_t)(b * 12 + o)) * NN + n;
        base[off] = val;
        if (base16) base16[off] = bf16of(val);
    }
}

// ---------------------------------------------------------------------------
// Kernel 2: t-feature table, bf16, MFMA-B-frag layout
// ---------------------------------------------------------------------------
__global__ void tfeat_kernel(unsigned short* __restrict__ tf16)
{
    int idx = blockIdx.x * blockDim.x + threadIdx.x;
    if (idx >= NSTEP * 16) return;
    int k = idx >> 4;
    int r = idx & 15;
    int hi = r >> 3;
    int j = r & 7;
    float ang = DTS * (float)k * (float)(j + 1);
    float v = hi ? sinf(ang) : cosf(ang);
    tf16[idx] = bf16of(v);
}

// ---------------------------------------------------------------------------
// Kernel 2b: U f32 [n][m] -> U16 bf16 [n][m]  and  UT16 bf16 [m][n]
// 64x64 tiles, LDS transpose.
// ---------------------------------------------------------------------------
__global__ __launch_bounds__(256) void u_convert_kernel(
    const float* __restrict__ U,
    unsigned short* __restrict__ U16,
    unsigned short* __restrict__ UT16)
{
    __shared__ unsigned short tile[64][66];
    const int t = threadIdx.x;
    const int bx = blockIdx.x;   // col tile (m)
    const int by = blockIdx.y;   // row tile (n)
    {
        int r  = t >> 2;           // 0..63
        int c0 = (t & 3) * 16;
        size_t gr = (size_t)(by * 64 + r);
        size_t gc = (size_t)(bx * 64) + c0;
        const float4* src = reinterpret_cast<const float4*>(U + gr * K4 + gc);
        unsigned ou[8];
#pragma unroll
        for (int i = 0; i < 4; ++i) {
            float4 v = src[i];
            ou[2 * i]     = pack2bf(v.y, v.x);
            ou[2 * i + 1] = pack2bf(v.w, v.z);
        }
        uint4* dst = reinterpret_cast<uint4*>(&U16[gr * K4 + gc]);
        dst[0] = make_uint4(ou[0], ou[1], ou[2], ou[3]);
        dst[1] = make_uint4(ou[4], ou[5], ou[6], ou[7]);
#pragma unroll
        for (int i = 0; i < 8; ++i) {
            tile[r][c0 + 2 * i]     = (unsigned short)(ou[i] & 0xFFFFu);
            tile[r][c0 + 2 * i + 1] = (unsigned short)(ou[i] >> 16);
        }
    }
    __syncthreads();
    {
        int c  = t >> 2;           // local col
        int r0 = (t & 3) * 16;
        unsigned ou[8];
#pragma unroll
        for (int i = 0; i < 8; ++i) {
            unsigned lo = tile[r0 + 2 * i][c];
            unsigned hi = tile[r0 + 2 * i + 1][c];
            ou[i] = lo | (hi << 16);
        }
        size_t gm = (size_t)(bx * 64 + c);
        size_t gn = (size_t)(by * 64) + r0;
        uint4* dst = reinterpret_cast<uint4*>(&UT16[gm * K4 + gn]);
        dst[0] = make_uint4(ou[0], ou[1], ou[2], ou[3]);
        dst[1] = make_uint4(ou[4], ou[5], ou[6], ou[7]);
    }
}

// ---------------------------------------------------------------------------
// MFMA GEMM:  D[M'][N'] = alpha * A·Bt^T   (both operands k-contiguous bf16)
//   A : [M'][4096], Bt : [N'][4096]
//   TRANS_STORE=false: C[d_m][d_n] = alpha*D        (GEMM1: C=xc f32)
//   TRANS_STORE=true : C[d_n][d_m] = C0 + alpha*D   (GEMM2: C=out, C0=base)
// Tile 128x128, BK=64, 4 waves (2x2) of 64x64, 32x32x16 mfma.
// LDS XOR-swizzle: byte ^= (row&7)<<4 within each 128B row.
// ---------------------------------------------------------------------------
template <bool TRANS_STORE>
__global__ __launch_bounds__(256) void gemm_mfma(
    const unsigned short* __restrict__ A,
    const unsigned short* __restrict__ Bt,
    const float* __restrict__ C0,
    float* __restrict__ C,
    const float* __restrict__ alpha_ptr,
    float alpha_const)
{
    __shared__ uint4 lds4[2][2048];   // [buf][A 16KB | B 16KB]
    unsigned char* ldsc = reinterpret_cast<unsigned char*>(&lds4[0][0]);

    const int tid  = threadIdx.x;
    const int lane = tid & 63;
    const int l31  = lane & 31;
    const int hi   = lane >> 5;
    const int w    = tid >> 6;
    const int wr   = w >> 1;
    const int wc   = w & 1;
    const int m0   = blockIdx.y * 128;
    const int n0   = blockIdx.x * 128;

    // staging map: thread covers 64B (4x16B) of each region; 2 threads/row
    const int srow = tid >> 1;                 // 0..127
    const int skb  = (tid & 1) * 64;           // linear k-byte base
    const unsigned char* gA = (const unsigned char*)A + ((size_t)(m0 + srow) * K4) * 2 + skb;
    const unsigned char* gB = (const unsigned char*)Bt + ((size_t)(n0 + srow) * K4) * 2 + skb;
    const int swrow = srow * 128;
    const int sswz  = (srow & 7) << 4;

    uint4 ra[4], rb[4];

    auto LOADG = [&](int kt) {
        const size_t kby = (size_t)kt * 128;
#pragma unroll
        for (int i = 0; i < 4; ++i)
            ra[i] = *reinterpret_cast<const uint4*>(gA + kby + i * 16);
#pragma unroll
        for (int i = 0; i < 4; ++i)
            rb[i] = *reinterpret_cast<const uint4*>(gB + kby + i * 16);
    };
    auto WRITE_LDS = [&](int buf) {
        unsigned char* p = ldsc + buf * 32768;
#pragma unroll
        for (int i = 0; i < 4; ++i)
            *reinterpret_cast<uint4*>(p + (swrow + ((skb + i * 16) ^ sswz))) = ra[i];
#pragma unroll
        for (int i = 0; i < 4; ++i)
            *reinterpret_cast<uint4*>(p + 16384 + (swrow + ((skb + i * 16) ^ sswz))) = rb[i];
    };

    f32x16 acc00 = fzero16(), acc01 = fzero16(), acc10 = fzero16(), acc11 = fzero16();

    const int raw0 = wr * 64 + l31;        // A rows for frags
    const int rbw0 = wc * 64 + l31;        // B rows
    const int khb  = hi * 16;              // k-half byte offset

    LOADG(0);
    WRITE_LDS(0);

    for (int kt = 0; kt < K4 / 64; ++kt) {
        __syncthreads();
        if (kt + 1 < K4 / 64) LOADG(kt + 1);
        const unsigned char* p = ldsc + (kt & 1) * 32768;
#pragma unroll
        for (int ks = 0; ks < 4; ++ks) {
            const int kc = ks * 32 + khb;
            short8 a0 = *reinterpret_cast<const short8*>(
                p + (raw0 * 128 + (kc ^ ((raw0 & 7) << 4))));
            short8 a1 = *reinterpret_cast<const short8*>(
                p + ((raw0 + 32) * 128 + (kc ^ ((raw0 & 7) << 4))));
            short8 b0 = *reinterpret_cast<const short8*>(
                p + 16384 + (rbw0 * 128 + (kc ^ ((rbw0 & 7) << 4))));
            short8 b1 = *reinterpret_cast<const short8*>(
                p + 16384 + ((rbw0 + 32) * 128 + (kc ^ ((rbw0 & 7) << 4))));
            acc00 = __builtin_amdgcn_mfma_f32_32x32x16_bf16(a0, b0, acc00, 0, 0, 0);
            acc01 = __builtin_amdgcn_mfma_f32_32x32x16_bf16(a0, b1, acc01, 0, 0, 0);
            acc10 = __builtin_amdgcn_mfma_f32_32x32x16_bf16(a1, b0, acc10, 0, 0, 0);
            acc11 = __builtin_amdgcn_mfma_f32_32x32x16_bf16(a1, b1, acc11, 0, 0, 0);
        }
        if (kt + 1 < K4 / 64) WRITE_LDS((kt + 1) & 1);
    }

    float alpha = alpha_const;
    if (alpha_ptr) alpha *= alpha_ptr[0];

#define EPI(ACC, MH, NH)                                                       \
    {                                                                          \
        if (!TRANS_STORE) {                                                    \
            int colg = n0 + wc * 64 + (NH) * 32 + l31;                         \
            int rowb = m0 + wr * 64 + (MH) * 32 + 4 * hi;                      \
            _Pragma("unroll")                                                  \
            for (int r = 0; r < 16; ++r) {                                     \
                int row = rowb + (r & 3) + 8 * (r >> 2);                       \
                C[(size_t)row * K4 + colg] = ACC[r] * alpha;                   \
            }                                                                  \
        } else {                                                               \
            int rowo = n0 + wc * 64 + (NH) * 32 + l31;                         \
            int mb   = m0 + wr * 64 + (MH) * 32 + 4 * hi;                      \
            _Pragma("unroll")                                                  \
            for (int q = 0; q < 4; ++q) {                                      \
                size_t off = (size_t)rowo * K4 + mb + 8 * q;                   \
                float4 c0v = *reinterpret_cast<const float4*>(&C0[off]);       \
                float4 v;                                                      \
                v.x = fmaf(ACC[4 * q + 0], alpha, c0v.x);                      \
                v.y = fmaf(ACC[4 * q + 1], alpha, c0v.y);                      \
                v.z = fmaf(ACC[4 * q + 2], alpha, c0v.z);                      \
                v.w = fmaf(ACC[4 * q + 3], alpha, c0v.w);                      \
                *reinterpret_cast<float4*>(&C[off]) = v;                       \
            }                                                                  \
        }                                                                      \
    }
    EPI(acc00, 0, 0) EPI(acc01, 0, 1) EPI(acc10, 1, 0) EPI(acc11, 1, 1)
#undef EPI
}

// ---------------------------------------------------------------------------
// Fallback f32 GEMM (used only if workspace too small)
// ---------------------------------------------------------------------------
#define GMT 64
#define GNT 64
#define GKT 32
#define GPAD 4

template <bool UT>
__global__ __launch_bounds__(256) void gemm_u(
    const float* __restrict__ X,
    const float* __restrict__ Uq,
    const float* __restrict__ C0,
    float* __restrict__ C,
    const float* __restrict__ alpha_ptr,
    float alpha_const)
{
    __shared__ float Xs[GKT][GMT + GPAD];
    __shared__ float Us[GKT][GNT + GPAD];

    const int t = threadIdx.x;
    const int m0 = blockIdx.y * GMT;
    const int n0 = blockIdx.x * GNT;
    const int tx = t & 15;
    const int ty = t >> 4;
    const int srow = t >> 2;
    const int scol = (t & 3) * 8;

    float acc[4][4] = {};

    for (int k0 = 0; k0 < NN; k0 += GKT) {
        {
            const float4* xp = reinterpret_cast<const float4*>(
                &X[(size_t)(m0 + srow) * NN + k0 + scol]);
            float4 a = xp[0], b4 = xp[1];
            Xs[scol + 0][srow] = a.x;  Xs[scol + 1][srow] = a.y;
            Xs[scol + 2][srow] = a.z;  Xs[scol + 3][srow] = a.w;
            Xs[scol + 4][srow] = b4.x; Xs[scol + 5][srow] = b4.y;
            Xs[scol + 6][srow] = b4.z; Xs[scol + 7][srow] = b4.w;
        }
        if (UT) {
            int kk = t >> 3;
            int j0 = (t & 7) * 8;
            const float4* up = reinterpret_cast<const float4*>(
                &Uq[(size_t)(k0 + kk) * NN + n0 + j0]);
            float4 a = up[0], b4 = up[1];
            Us[kk][j0 + 0] = a.x;  Us[kk][j0 + 1] = a.y;
            Us[kk][j0 + 2] = a.z;  Us[kk][j0 + 3] = a.w;
            Us[kk][j0 + 4] = b4.x; Us[kk][j0 + 5] = b4.y;
            Us[kk][j0 + 6] = b4.z; Us[kk][j0 + 7] = b4.w;
        } else {
            const float4* up = reinterpret_cast<const float4*>(
                &Uq[(size_t)(n0 + srow) * NN + k0 + scol]);
            float4 a = up[0], b4 = up[1];
            Us[scol + 0][srow] = a.x;  Us[scol + 1][srow] = a.y;
            Us[scol + 2][srow] = a.z;  Us[scol + 3][srow] = a.w;
            Us[scol + 4][srow] = b4.x; Us[scol + 5][srow] = b4.y;
            Us[scol + 6][srow] = b4.z; Us[scol + 7][srow] = b4.w;
        }
        __syncthreads();
#pragma unroll
        for (int kk = 0; kk < GKT; ++kk) {
            float a[4], bb[4];
#pragma unroll
            for (int i = 0; i < 4; ++i) a[i] = Xs[kk][ty * 4 + i];
#pragma unroll
            for (int j = 0; j < 4; ++j) bb[j] = Us[kk][tx * 4 + j];
#pragma unroll
            for (int i = 0; i < 4; ++i)
#pragma unroll
                for (int j = 0; j < 4; ++j)
                    acc[i][j] = fmaf(a[i], bb[j], acc[i][j]);
        }
        __syncthreads();
    }

    float alpha = alpha_const;
    if (alpha_ptr) alpha *= alpha_ptr[0];

#pragma unroll
    for (int i = 0; i < 4; ++i) {
        int row = m0 + ty * 4 + i;
        size_t off = (size_t)row * NN + n0 + tx * 4;
        float4 v;
        v.x = acc[i][0] * alpha;
        v.y = acc[i][1] * alpha;
        v.z = acc[i][2] * alpha;
        v.w = acc[i][3] * alpha;
        if (C0) {
            float4 c0 = *reinterpret_cast<const float4*>(&C0[off]);
            v.x += c0.x; v.y += c0.y; v.z += c0.z; v.w += c0.w;
        }
        *reinterpret_cast<float4*>(&C[off]) = v;
    }
}

// ---------------------------------------------------------------------------
// Kernel 3: fused Euler ODE via MFMA (unchanged from R3 except bf16 output)
// ---------------------------------------------------------------------------
__global__ __launch_bounds__(256) void ode_kernel(
    const float* __restrict__ x0,
    float* __restrict__ xc,                    // in: cond_spec
    const unsigned short* __restrict__ tf16,   // [10][16] bf16 t-features
    const float* __restrict__ A1,
    const float* __restrict__ B1,
    const float* __restrict__ b1,
    const float* __restrict__ W2,
    const float* __restrict__ b2,
    unsigned short* __restrict__ xf16)         // nullable bf16 out [384][4096]
{
    const int tid  = threadIdx.x;
    const int lane = tid & 63;
    const int e31  = lane & 31;
    const int hi   = lane >> 5;
    const int wv   = tid >> 6;
    const size_t eg = (size_t)blockIdx.x * 128 + (size_t)wv * 32 + e31;

    FragU af[2][3];
#pragma unroll
    for (int mt = 0; mt < 2; ++mt) {
        int h = mt * 32 + e31;
#pragma unroll
        for (int c = 0; c < 3; ++c) {
            const float* wp = (hi ? B1 : A1) + (size_t)(h * 3 + c) * 8;
            float4 f0 = *reinterpret_cast<const float4*>(wp);
            float4 f1 = *reinterpret_cast<const float4*>(wp + 4);
            af[mt][c].u[0] = pack2bf(f0.y * L2E, f0.x * L2E);
            af[mt][c].u[1] = pack2bf(f0.w * L2E, f0.z * L2E);
            af[mt][c].u[2] = pack2bf(f1.y * L2E, f1.x * L2E);
            af[mt][c].u[3] = pack2bf(f1.w * L2E, f1.z * L2E);
        }
    }

    f32x16 ci0, ci1;
    float w2v0[16], w2v1[16];
#pragma unroll
    for (int r = 0; r < 16; ++r) {
        int row = (r & 3) + 8 * (r >> 2) + 4 * hi;
        ci0[r] = b1[row] * L2E;
        ci1[r] = b1[32 + row] * L2E;
        w2v0[r] = W2[row] * LN2;
        w2v1[r] = W2[32 + row] * LN2;
    }

    float x   = x0[eg];
    float cnd = xc[eg];
    const float db2 = DTS * b2[0];

    FragU bc;
    {
        float s, c;
        __sincosf(cnd, &s, &c);
        float cg[8], sg[8];
        cg[0] = c; sg[0] = s;
#pragma unroll
        for (int g = 1; g < 8; ++g) {
            cg[g] = cg[g - 1] * c - sg[g - 1] * s;
            sg[g] = sg[g - 1] * c + cg[g - 1] * s;
        }
#pragma unroll
        for (int t = 0; t < 4; ++t) {
            float a0 = hi ? sg[2 * t]     : cg[2 * t];
            float a1 = hi ? sg[2 * t + 1] : cg[2 * t + 1];
            bc.u[t] = pack2bf(a1, a0);
        }
    }

    FragU bt;
    bt.v = *reinterpret_cast<const uint4*>(tf16 + hi * 8);

#pragma unroll 1
    for (int k = 0; k < NSTEP; ++k) {
        float s, c;
        __sincosf(x, &s, &c);
        float cg[8], sg[8];
        cg[0] = c; sg[0] = s;
#pragma unroll
        for (int g = 1; g < 8; ++g) {
            cg[g] = cg[g - 1] * c - sg[g - 1] * s;
            sg[g] = sg[g - 1] * c + cg[g - 1] * s;
        }
        FragU bx;
#pragma unroll
        for (int t = 0; t < 4; ++t) {
            float a0 = hi ? sg[2 * t]     : cg[2 * t];
            float a1 = hi ? sg[2 * t + 1] : cg[2 * t + 1];
            bx.u[t] = pack2bf(a1, a0);
        }

        FragU btn;
        int kn = (k + 1 < NSTEP) ? (k + 1) : (NSTEP - 1);
        btn.v = *reinterpret_cast<const uint4*>(tf16 + kn * 16 + hi * 8);

        f32x16 a0 = __builtin_amdgcn_mfma_f32_32x32x16_bf16(af[0][0].s, bx.s, ci0, 0, 0, 0);
        f32x16 a1v = __builtin_amdgcn_mfma_f32_32x32x16_bf16(af[1][0].s, bx.s, ci1, 0, 0, 0);
        a0  = __builtin_amdgcn_mfma_f32_32x32x16_bf16(af[0][1].s, bc.s, a0, 0, 0, 0);
        a1v = __builtin_amdgcn_mfma_f32_32x32x16_bf16(af[1][1].s, bc.s, a1v, 0, 0, 0);
        a0  = __builtin_amdgcn_mfma_f32_32x32x16_bf16(af[0][2].s, bt.s, a0, 0, 0, 0);
        a1v = __builtin_amdgcn_mfma_f32_32x32x16_bf16(af[1][2].s, bt.s, a1v, 0, 0, 0);

        float dot = 0.f;
#pragma unroll
        for (int r = 0; r < 16; ++r) {
            float q = a0[r];
            float sgm = __builtin_amdgcn_rcpf(1.f + exp2f(-q));
            dot = fmaf(q * sgm, w2v0[r], dot);
        }
#pragma unroll
        for (int r = 0; r < 16; ++r) {
            float q = a1v[r];
            float sgm = __builtin_amdgcn_rcpf(1.f + exp2f(-q));
            dot = fmaf(q * sgm, w2v1[r], dot);
        }
        float other = __shfl_xor(dot, 32, 64);
        dot += other;
        x = fmaf(DTS, dot, x) + db2;
        bt = btn;
    }

    if (xf16) {
        if (!hi) xf16[eg] = bf16of(x);
    } else {
        if (!hi) xc[eg] = x;
    }
}

// ---------------------------------------------------------------------------
extern "C" void kernel_launch(void* const* d_in, const int* in_sizes, int n_in,
                              void* d_out, int out_size, void* d_ws, size_t ws_size,
                              hipStream_t stream) {
    const float* hd  = (const float*)d_in[0];
    const float* x0  = (const float*)d_in[1];
    const float* U   = (const float*)d_in[2];
    const float* Wk  = (const float*)d_in[3];
    const float* bk  = (const float*)d_in[4];
    const float* Wad = (const float*)d_in[5];
    const float* bad = (const float*)d_in[6];
    const float* kg  = (const float*)d_in[7];
    const float* fg  = (const float*)d_in[8];
    const float* A1  = (const float*)d_in[9];
    const float* B1  = (const float*)d_in[10];
    const float* b1  = (const float*)d_in[11];
    const float* W2  = (const float*)d_in[12];
    const float* b2  = (const float*)d_in[13];
    float* out = (float*)d_out;

    unsigned char* ws = (unsigned char*)d_ws;
    // byte offsets
    const size_t offBase = 0;                       // base f32, 6291456 B
    const size_t offXC   = 6291456;                 // xc f32,   6291456 B
    const size_t offTF   = 12582912;                // tf16, 320 B (pad 1024)
    const size_t offB16  = 12583936;                // base16, 3145728 B
    const size_t offXF   = 15729664;                // xf16,   3145728 B
    const size_t offU16  = 18875392;                // 33554432 B
    const size_t offUT   = 52429824;                // 33554432 B
    const size_t needFast = 85984256;

    float* base = (float*)(ws + offBase);
    float* xc   = (float*)(ws + offXC);
    unsigned short* tf16 = (unsigned short*)(ws + offTF);

    const bool fast = (ws_size >= needFast);

    if (fast) {
        unsigned short* base16 = (unsigned short*)(ws + offB16);
        unsigned short* xf16   = (unsigned short*)(ws + offXF);
        unsigned short* U16    = (unsigned short*)(ws + offU16);
        unsigned short* UT16   = (unsigned short*)(ws + offUT);

        u_convert_kernel<<<dim3(64, 64), 256, 0, stream>>>(U, U16, UT16);
        base_pred_kernel<<<(BB * NN) / 256, 256, 0, stream>>>(
            hd, Wk, bk, Wad, bad, kg, base, base16);
        tfeat_kernel<<<1, 256, 0, stream>>>(tf16);
        // GEMM1: xc[row][m] = (1/64) * sum_k base16[row][k] * UT16[m][k]
        gemm_mfma<false><<<dim3(NN / 128, BLN / 128), 256, 0, stream>>>(
            base16, UT16, nullptr, xc, nullptr, 1.0f / 64.0f);
        // ODE: cond -> x_final (bf16, natural layout)
        ode_kernel<<<ELEMS / 128, 256, 0, stream>>>(
            x0, xc, tf16, A1, B1, b1, W2, b2, xf16);
        // GEMM2: out[row][m] = base + fg*64 * sum_k U16[m][k] * xf16[row][k]
        gemm_mfma<true><<<dim3(BLN / 128, NN / 128), 256, 0, stream>>>(
            U16, xf16, base, out, fg, 64.0f);
    } else {
        base_pred_kernel<<<(BB * NN) / 256, 256, 0, stream>>>(
            hd, Wk, bk, Wad, bad, kg, base, nullptr);
        tfeat_kernel<<<1, 256, 0, stream>>>(tf16);
        gemm_u<true><<<dim3(NN / GNT, BLN / GMT), 256, 0, stream>>>(
            base, U, nullptr, xc, nullptr, 1.0f / 64.0f);
        ode_kernel<<<ELEMS / 128, 256, 0, stream>>>(
            x0, xc, tf16, A1, B1, b1, W2, b2, nullptr);
        gemm_u<false><<<dim3(NN / GNT, BLN / GMT), 256, 0, stream>>>(
            xc, U, base, out, fg, 64.0f);
    }
}

// Round 5
// 590.228 us; speedup vs baseline: 3.9816x; 1.1207x over previous
//
#include <hip/hip_runtime.h>
#include <hip/hip_bf16.h>
#include <math.h>

// Problem dims (fixed by reference)
#define BB 32
#define LL 12
#define NN 4096
#define CIN 4
#define HID 64
#define GRID_F 8
#define NSTEP 10
#define DTS 0.1f
#define BLN (BB*LL)          // 384 rows (b*L+l)
#define ELEMS (BB*LL*NN)     // 1572864
#define K4 4096

#define L2E 1.4426950408889634f
#define LN2 0.6931471805599453f

typedef __attribute__((ext_vector_type(8))) short short8;
typedef __attribute__((ext_vector_type(16))) float f32x16;

union FragU { unsigned u[4]; uint4 v; short8 s; };

__device__ __forceinline__ unsigned pack2bf(float a, float b) {
    // a -> high 16 bits, b -> low 16 bits (both RNE-rounded bf16)
    unsigned ua = __float_as_uint(a);
    unsigned ub = __float_as_uint(b);
    ua += 0x7FFFu + ((ua >> 16) & 1u);
    ub += 0x7FFFu + ((ub >> 16) & 1u);
    return (ua & 0xFFFF0000u) | (ub >> 16);
}

__device__ __forceinline__ unsigned short bf16of(float a) {
    unsigned ua = __float_as_uint(a);
    ua += 0x7FFFu + ((ua >> 16) & 1u);
    return (unsigned short)(ua >> 16);
}

__device__ __forceinline__ f32x16 fzero16() {
    f32x16 z;
#pragma unroll
    for (int i = 0; i < 16; ++i) z[i] = 0.f;
    return z;
}

// ---------------------------------------------------------------------------
// Kernel 1: base_pred[b,l,n] = prior + tanh(adapter)*kasa_gate  (f32 + bf16)
// ---------------------------------------------------------------------------
__global__ __launch_bounds__(256) void base_pred_kernel(
    const float* __restrict__ hd,   // [B][L][N][4]
    const float* __restrict__ Wk,   // [12][12]
    const float* __restrict__ bk,   // [12]
    const float* __restrict__ Wad,  // [12][12]
    const float* __restrict__ bad,  // [12]
    const float* __restrict__ kgp,  // scalar
    float* __restrict__ base,       // [384][4096]
    unsigned short* __restrict__ base16)  // nullable [384][4096] bf16
{
    int idx = blockIdx.x * 256 + threadIdx.x;     // 0 .. 131071  (b,n)
    int b = idx >> 12;
    int n = idx & 4095;
    const float* hb = hd + (size_t)b * (LL * NN * CIN) + (size_t)n * CIN;

    float h0[12];
    float prior = 0.f;
#pragma unroll
    for (int t = 0; t < 12; ++t) {
        float4 v = *reinterpret_cast<const float4*>(hb + (size_t)t * (NN * CIN));
        h0[t] = v.x;
        if (t == 11) prior = v.w;
    }
    float kgate = kgp[0];

    float kr[12];
#pragma unroll
    for (int l = 0; l < 12; ++l) {
        float p = bk[l];
#pragma unroll
        for (int t = 0; t < 12; ++t) p = fmaf(h0[t], Wk[l * 12 + t], p);
        kr[l] = p;
    }
#pragma unroll
    for (int o = 0; o < 12; ++o) {
        float p = bad[o];
#pragma unroll
        for (int l = 0; l < 12; ++l) p = fmaf(kr[l], Wad[o * 12 + l], p);
        float val = prior + tanhf(p) * kgate;
        size_t off = ((size_t)(b * 12 + o)) * NN + n;
        base[off] = val;
        if (base16) base16[off] = bf16of(val);
    }
}

// ---------------------------------------------------------------------------
// Kernel 2: t-feature table, bf16, MFMA-B-frag layout
// ---------------------------------------------------------------------------
__global__ void tfeat_kernel(unsigned short* __restrict__ tf16)
{
    int idx = blockIdx.x * blockDim.x + threadIdx.x;
    if (idx >= NSTEP * 16) return;
    int k = idx >> 4;
    int r = idx & 15;
    int hi = r >> 3;
    int j = r & 7;
    float ang = DTS * (float)k * (float)(j + 1);
    float v = hi ? sinf(ang) : cosf(ang);
    tf16[idx] = bf16of(v);
}

// ---------------------------------------------------------------------------
// Kernel 2b: U f32 [n][m] -> U16 bf16 [n][m]  and  UT16 bf16 [m][n]
// ---------------------------------------------------------------------------
__global__ __launch_bounds__(256) void u_convert_kernel(
    const float* __restrict__ U,
    unsigned short* __restrict__ U16,
    unsigned short* __restrict__ UT16)
{
    __shared__ unsigned short tile[64][66];
    const int t = threadIdx.x;
    const int bx = blockIdx.x;   // col tile (m)
    const int by = blockIdx.y;   // row tile (n)
    {
        int r  = t >> 2;           // 0..63
        int c0 = (t & 3) * 16;
        size_t gr = (size_t)(by * 64 + r);
        size_t gc = (size_t)(bx * 64) + c0;
        const float4* src = reinterpret_cast<const float4*>(U + gr * K4 + gc);
        unsigned ou[8];
#pragma unroll
        for (int i = 0; i < 4; ++i) {
            float4 v = src[i];
            ou[2 * i]     = pack2bf(v.y, v.x);
            ou[2 * i + 1] = pack2bf(v.w, v.z);
        }
        uint4* dst = reinterpret_cast<uint4*>(&U16[gr * K4 + gc]);
        dst[0] = make_uint4(ou[0], ou[1], ou[2], ou[3]);
        dst[1] = make_uint4(ou[4], ou[5], ou[6], ou[7]);
#pragma unroll
        for (int i = 0; i < 8; ++i) {
            tile[r][c0 + 2 * i]     = (unsigned short)(ou[i] & 0xFFFFu);
            tile[r][c0 + 2 * i + 1] = (unsigned short)(ou[i] >> 16);
        }
    }
    __syncthreads();
    {
        int c  = t >> 2;           // local col
        int r0 = (t & 3) * 16;
        unsigned ou[8];
#pragma unroll
        for (int i = 0; i < 8; ++i) {
            unsigned lo = tile[r0 + 2 * i][c];
            unsigned hi = tile[r0 + 2 * i + 1][c];
            ou[i] = lo | (hi << 16);
        }
        size_t gm = (size_t)(bx * 64 + c);
        size_t gn = (size_t)(by * 64) + r0;
        uint4* dst = reinterpret_cast<uint4*>(&UT16[gm * K4 + gn]);
        dst[0] = make_uint4(ou[0], ou[1], ou[2], ou[3]);
        dst[1] = make_uint4(ou[4], ou[5], ou[6], ou[7]);
    }
}

// ---------------------------------------------------------------------------
// MFMA GEMM:  D[M'][N'] = alpha * A·Bt^T   (both operands k-contiguous bf16)
//   TRANS_STORE=false: C[d_m][d_n] = alpha*D        (GEMM1: C=xc f32)
//   TRANS_STORE=true : C[d_n][d_m] = C0 + alpha*D   (GEMM2: C=out, C0=base)
// Tile 128x128, BK=64, 4 waves (2x2) of 64x64, 32x32x16 mfma.
// LDS XOR-swizzle: byte ^= (row&7)<<4 within each 128B row.
// ---------------------------------------------------------------------------
template <bool TRANS_STORE>
__global__ __launch_bounds__(256) void gemm_mfma(
    const unsigned short* __restrict__ A,
    const unsigned short* __restrict__ Bt,
    const float* __restrict__ C0,
    float* __restrict__ C,
    const float* __restrict__ alpha_ptr,
    float alpha_const)
{
    __shared__ uint4 lds4[2][2048];   // [buf][A 16KB | B 16KB]
    unsigned char* ldsc = reinterpret_cast<unsigned char*>(&lds4[0][0]);

    const int tid  = threadIdx.x;
    const int lane = tid & 63;
    const int l31  = lane & 31;
    const int hi   = lane >> 5;
    const int w    = tid >> 6;
    const int wr   = w >> 1;
    const int wc   = w & 1;
    const int m0   = blockIdx.y * 128;
    const int n0   = blockIdx.x * 128;

    const int srow = tid >> 1;                 // 0..127
    const int skb  = (tid & 1) * 64;           // linear k-byte base
    const unsigned char* gA = (const unsigned char*)A + ((size_t)(m0 + srow) * K4) * 2 + skb;
    const unsigned char* gB = (const unsigned char*)Bt + ((size_t)(n0 + srow) * K4) * 2 + skb;
    const int swrow = srow * 128;
    const int sswz  = (srow & 7) << 4;

    uint4 ra[4], rb[4];

    auto LOADG = [&](int kt) {
        const size_t kby = (size_t)kt * 128;
#pragma unroll
        for (int i = 0; i < 4; ++i)
            ra[i] = *reinterpret_cast<const uint4*>(gA + kby + i * 16);
#pragma unroll
        for (int i = 0; i < 4; ++i)
            rb[i] = *reinterpret_cast<const uint4*>(gB + kby + i * 16);
    };
    auto WRITE_LDS = [&](int buf) {
        unsigned char* p = ldsc + buf * 32768;
#pragma unroll
        for (int i = 0; i < 4; ++i)
            *reinterpret_cast<uint4*>(p + (swrow + ((skb + i * 16) ^ sswz))) = ra[i];
#pragma unroll
        for (int i = 0; i < 4; ++i)
            *reinterpret_cast<uint4*>(p + 16384 + (swrow + ((skb + i * 16) ^ sswz))) = rb[i];
    };

    f32x16 acc00 = fzero16(), acc01 = fzero16(), acc10 = fzero16(), acc11 = fzero16();

    const int raw0 = wr * 64 + l31;        // A rows for frags
    const int rbw0 = wc * 64 + l31;        // B rows
    const int khb  = hi * 16;              // k-half byte offset

    LOADG(0);
    WRITE_LDS(0);

    for (int kt = 0; kt < K4 / 64; ++kt) {
        __syncthreads();
        if (kt + 1 < K4 / 64) LOADG(kt + 1);
        const unsigned char* p = ldsc + (kt & 1) * 32768;
#pragma unroll
        for (int ks = 0; ks < 4; ++ks) {
            const int kc = ks * 32 + khb;
            short8 a0 = *reinterpret_cast<const short8*>(
                p + (raw0 * 128 + (kc ^ ((raw0 & 7) << 4))));
            short8 a1 = *reinterpret_cast<const short8*>(
                p + ((raw0 + 32) * 128 + (kc ^ ((raw0 & 7) << 4))));
            short8 b0 = *reinterpret_cast<const short8*>(
                p + 16384 + (rbw0 * 128 + (kc ^ ((rbw0 & 7) << 4))));
            short8 b1 = *reinterpret_cast<const short8*>(
                p + 16384 + ((rbw0 + 32) * 128 + (kc ^ ((rbw0 & 7) << 4))));
            acc00 = __builtin_amdgcn_mfma_f32_32x32x16_bf16(a0, b0, acc00, 0, 0, 0);
            acc01 = __builtin_amdgcn_mfma_f32_32x32x16_bf16(a0, b1, acc01, 0, 0, 0);
            acc10 = __builtin_amdgcn_mfma_f32_32x32x16_bf16(a1, b0, acc10, 0, 0, 0);
            acc11 = __builtin_amdgcn_mfma_f32_32x32x16_bf16(a1, b1, acc11, 0, 0, 0);
        }
        if (kt + 1 < K4 / 64) WRITE_LDS((kt + 1) & 1);
    }

    float alpha = alpha_const;
    if (alpha_ptr) alpha *= alpha_ptr[0];

#define EPI(ACC, MH, NH)                                                       \
    {                                                                          \
        if (!TRANS_STORE) {                                                    \
            int colg = n0 + wc * 64 + (NH) * 32 + l31;                         \
            int rowb = m0 + wr * 64 + (MH) * 32 + 4 * hi;                      \
            _Pragma("unroll")                                                  \
            for (int r = 0; r < 16; ++r) {                                     \
                int row = rowb + (r & 3) + 8 * (r >> 2);                       \
                C[(size_t)row * K4 + colg] = ACC[r] * alpha;                   \
            }                                                                  \
        } else {                                                               \
            int rowo = n0 + wc * 64 + (NH) * 32 + l31;                         \
            int mb   = m0 + wr * 64 + (MH) * 32 + 4 * hi;                      \
            _Pragma("unroll")                                                  \
            for (int q = 0; q < 4; ++q) {                                      \
                size_t off = (size_t)rowo * K4 + mb + 8 * q;                   \
                float4 c0v = *reinterpret_cast<const float4*>(&C0[off]);       \
                float4 v;                                                      \
                v.x = fmaf(ACC[4 * q + 0], alpha, c0v.x);                      \
                v.y = fmaf(ACC[4 * q + 1], alpha, c0v.y);                      \
                v.z = fmaf(ACC[4 * q + 2], alpha, c0v.z);                      \
                v.w = fmaf(ACC[4 * q + 3], alpha, c0v.w);                      \
                *reinterpret_cast<float4*>(&C[off]) = v;                       \
            }                                                                  \
        }                                                                      \
    }
    EPI(acc00, 0, 0) EPI(acc01, 0, 1) EPI(acc10, 1, 0) EPI(acc11, 1, 1)
#undef EPI
}

// ---------------------------------------------------------------------------
// Fallback f32 GEMM (used only if workspace too small)
// ---------------------------------------------------------------------------
#define GMT 64
#define GNT 64
#define GKT 32
#define GPAD 4

template <bool UT>
__global__ __launch_bounds__(256) void gemm_u(
    const float* __restrict__ X,
    const float* __restrict__ Uq,
    const float* __restrict__ C0,
    float* __restrict__ C,
    const float* __restrict__ alpha_ptr,
    float alpha_const)
{
    __shared__ float Xs[GKT][GMT + GPAD];
    __shared__ float Us[GKT][GNT + GPAD];

    const int t = threadIdx.x;
    const int m0 = blockIdx.y * GMT;
    const int n0 = blockIdx.x * GNT;
    const int tx = t & 15;
    const int ty = t >> 4;
    const int srow = t >> 2;
    const int scol = (t & 3) * 8;

    float acc[4][4] = {};

    for (int k0 = 0; k0 < NN; k0 += GKT) {
        {
            const float4* xp = reinterpret_cast<const float4*>(
                &X[(size_t)(m0 + srow) * NN + k0 + scol]);
            float4 a = xp[0], b4 = xp[1];
            Xs[scol + 0][srow] = a.x;  Xs[scol + 1][srow] = a.y;
            Xs[scol + 2][srow] = a.z;  Xs[scol + 3][srow] = a.w;
            Xs[scol + 4][srow] = b4.x; Xs[scol + 5][srow] = b4.y;
            Xs[scol + 6][srow] = b4.z; Xs[scol + 7][srow] = b4.w;
        }
        if (UT) {
            int kk = t >> 3;
            int j0 = (t & 7) * 8;
            const float4* up = reinterpret_cast<const float4*>(
                &Uq[(size_t)(k0 + kk) * NN + n0 + j0]);
            float4 a = up[0], b4 = up[1];
            Us[kk][j0 + 0] = a.x;  Us[kk][j0 + 1] = a.y;
            Us[kk][j0 + 2] = a.z;  Us[kk][j0 + 3] = a.w;
            Us[kk][j0 + 4] = b4.x; Us[kk][j0 + 5] = b4.y;
            Us[kk][j0 + 6] = b4.z; Us[kk][j0 + 7] = b4.w;
        } else {
            const float4* up = reinterpret_cast<const float4*>(
                &Uq[(size_t)(n0 + srow) * NN + k0 + scol]);
            float4 a = up[0], b4 = up[1];
            Us[scol + 0][srow] = a.x;  Us[scol + 1][srow] = a.y;
            Us[scol + 2][srow] = a.z;  Us[scol + 3][srow] = a.w;
            Us[scol + 4][srow] = b4.x; Us[scol + 5][srow] = b4.y;
            Us[scol + 6][srow] = b4.z; Us[scol + 7][srow] = b4.w;
        }
        __syncthreads();
#pragma unroll
        for (int kk = 0; kk < GKT; ++kk) {
            float a[4], bb[4];
#pragma unroll
            for (int i = 0; i < 4; ++i) a[i] = Xs[kk][ty * 4 + i];
#pragma unroll
            for (int j = 0; j < 4; ++j) bb[j] = Us[kk][tx * 4 + j];
#pragma unroll
            for (int i = 0; i < 4; ++i)
#pragma unroll
                for (int j = 0; j < 4; ++j)
                    acc[i][j] = fmaf(a[i], bb[j], acc[i][j]);
        }
        __syncthreads();
    }

    float alpha = alpha_const;
    if (alpha_ptr) alpha *= alpha_ptr[0];

#pragma unroll
    for (int i = 0; i < 4; ++i) {
        int row = m0 + ty * 4 + i;
        size_t off = (size_t)row * NN + n0 + tx * 4;
        float4 v;
        v.x = acc[i][0] * alpha;
        v.y = acc[i][1] * alpha;
        v.z = acc[i][2] * alpha;
        v.w = acc[i][3] * alpha;
        if (C0) {
            float4 c0 = *reinterpret_cast<const float4*>(&C0[off]);
            v.x += c0.x; v.y += c0.y; v.z += c0.z; v.w += c0.w;
        }
        *reinterpret_cast<float4*>(&C[off]) = v;
    }
}

// ---------------------------------------------------------------------------
// Kernel 3: fused Euler ODE via MFMA.
//  v3: phase-batched silu with raw v_exp_f32 / v_rcp_f32 and 4 independent
//  dot accumulators (ILP within the wave, no libm denormal guards).
// ---------------------------------------------------------------------------
__global__ __launch_bounds__(256) void ode_kernel(
    const float* __restrict__ x0,
    float* __restrict__ xc,                    // in: cond_spec
    const unsigned short* __restrict__ tf16,   // [10][16] bf16 t-features
    const float* __restrict__ A1,
    const float* __restrict__ B1,
    const float* __restrict__ b1,
    const float* __restrict__ W2,
    const float* __restrict__ b2,
    unsigned short* __restrict__ xf16)         // nullable bf16 out [384][4096]
{
    const int tid  = threadIdx.x;
    const int lane = tid & 63;
    const int e31  = lane & 31;
    const int hi   = lane >> 5;
    const int wv   = tid >> 6;
    const size_t eg = (size_t)blockIdx.x * 128 + (size_t)wv * 32 + e31;

    FragU af[2][3];
#pragma unroll
    for (int mt = 0; mt < 2; ++mt) {
        int h = mt * 32 + e31;
#pragma unroll
        for (int c = 0; c < 3; ++c) {
            const float* wp = (hi ? B1 : A1) + (size_t)(h * 3 + c) * 8;
            float4 f0 = *reinterpret_cast<const float4*>(wp);
            float4 f1 = *reinterpret_cast<const float4*>(wp + 4);
            af[mt][c].u[0] = pack2bf(f0.y * L2E, f0.x * L2E);
            af[mt][c].u[1] = pack2bf(f0.w * L2E, f0.z * L2E);
            af[mt][c].u[2] = pack2bf(f1.y * L2E, f1.x * L2E);
            af[mt][c].u[3] = pack2bf(f1.w * L2E, f1.z * L2E);
        }
    }

    f32x16 ci0, ci1;
    float w2v0[16], w2v1[16];
#pragma unroll
    for (int r = 0; r < 16; ++r) {
        int row = (r & 3) + 8 * (r >> 2) + 4 * hi;
        ci0[r] = b1[row] * L2E;
        ci1[r] = b1[32 + row] * L2E;
        w2v0[r] = W2[row] * LN2;
        w2v1[r] = W2[32 + row] * LN2;
    }

    float x   = x0[eg];
    float cnd = xc[eg];
    const float db2 = DTS * b2[0];

    FragU bc;
    {
        float s, c;
        __sincosf(cnd, &s, &c);
        float cg[8], sg[8];
        cg[0] = c; sg[0] = s;
#pragma unroll
        for (int g = 1; g < 8; ++g) {
            cg[g] = cg[g - 1] * c - sg[g - 1] * s;
            sg[g] = sg[g - 1] * c + cg[g - 1] * s;
        }
#pragma unroll
        for (int t = 0; t < 4; ++t) {
            float a0 = hi ? sg[2 * t]     : cg[2 * t];
            float a1 = hi ? sg[2 * t + 1] : cg[2 * t + 1];
            bc.u[t] = pack2bf(a1, a0);
        }
    }

    FragU bt;
    bt.v = *reinterpret_cast<const uint4*>(tf16 + hi * 8);

#pragma unroll 1
    for (int k = 0; k < NSTEP; ++k) {
        float s, c;
        __sincosf(x, &s, &c);
        float cg[8], sg[8];
        cg[0] = c; sg[0] = s;
#pragma unroll
        for (int g = 1; g < 8; ++g) {
            cg[g] = cg[g - 1] * c - sg[g - 1] * s;
            sg[g] = sg[g - 1] * c + cg[g - 1] * s;
        }
        FragU bx;
#pragma unroll
        for (int t = 0; t < 4; ++t) {
            float a0f = hi ? sg[2 * t]     : cg[2 * t];
            float a1f = hi ? sg[2 * t + 1] : cg[2 * t + 1];
            bx.u[t] = pack2bf(a1f, a0f);
        }

        FragU btn;
        int kn = (k + 1 < NSTEP) ? (k + 1) : (NSTEP - 1);
        btn.v = *reinterpret_cast<const uint4*>(tf16 + kn * 16 + hi * 8);

        f32x16 a0 = __builtin_amdgcn_mfma_f32_32x32x16_bf16(af[0][0].s, bx.s, ci0, 0, 0, 0);
        f32x16 a1v = __builtin_amdgcn_mfma_f32_32x32x16_bf16(af[1][0].s, bx.s, ci1, 0, 0, 0);
        a0  = __builtin_amdgcn_mfma_f32_32x32x16_bf16(af[0][1].s, bc.s, a0, 0, 0, 0);
        a1v = __builtin_amdgcn_mfma_f32_32x32x16_bf16(af[1][1].s, bc.s, a1v, 0, 0, 0);
        a0  = __builtin_amdgcn_mfma_f32_32x32x16_bf16(af[0][2].s, bt.s, a0, 0, 0, 0);
        a1v = __builtin_amdgcn_mfma_f32_32x32x16_bf16(af[1][2].s, bt.s, a1v, 0, 0, 0);

        // ---- phase-batched silu: raw exp batch -> add+rcp batch -> dot ----
        float er0[16], er1[16];
#pragma unroll
        for (int r = 0; r < 16; ++r) er0[r] = __builtin_amdgcn_exp2f(-a0[r]);
#pragma unroll
        for (int r = 0; r < 16; ++r) er1[r] = __builtin_amdgcn_exp2f(-a1v[r]);
#pragma unroll
        for (int r = 0; r < 16; ++r) er0[r] = __builtin_amdgcn_rcpf(1.f + er0[r]);
#pragma unroll
        for (int r = 0; r < 16; ++r) er1[r] = __builtin_amdgcn_rcpf(1.f + er1[r]);

        float d0 = 0.f, d1 = 0.f, d2 = 0.f, d3 = 0.f;
#pragma unroll
        for (int r = 0; r < 4; ++r) {
            d0 = fmaf(a0[4 * r + 0] * w2v0[4 * r + 0], er0[4 * r + 0], d0);
            d1 = fmaf(a0[4 * r + 1] * w2v0[4 * r + 1], er0[4 * r + 1], d1);
            d2 = fmaf(a0[4 * r + 2] * w2v0[4 * r + 2], er0[4 * r + 2], d2);
            d3 = fmaf(a0[4 * r + 3] * w2v0[4 * r + 3], er0[4 * r + 3], d3);
        }
#pragma unroll
        for (int r = 0; r < 4; ++r) {
            d0 = fmaf(a1v[4 * r + 0] * w2v1[4 * r + 0], er1[4 * r + 0], d0);
            d1 = fmaf(a1v[4 * r + 1] * w2v1[4 * r + 1], er1[4 * r + 1], d1);
            d2 = fmaf(a1v[4 * r + 2] * w2v1[4 * r + 2], er1[4 * r + 2], d2);
            d3 = fmaf(a1v[4 * r + 3] * w2v1[4 * r + 3], er1[4 * r + 3], d3);
        }
        float dot = (d0 + d1) + (d2 + d3);
        float other = __shfl_xor(dot, 32, 64);
        dot += other;
        x = fmaf(DTS, dot, x) + db2;
        bt = btn;
    }

    if (xf16) {
        if (!hi) xf16[eg] = bf16of(x);
    } else {
        if (!hi) xc[eg] = x;
    }
}

// ---------------------------------------------------------------------------
extern "C" void kernel_launch(void* const* d_in, const int* in_sizes, int n_in,
                              void* d_out, int out_size, void* d_ws, size_t ws_size,
                              hipStream_t stream) {
    const float* hd  = (const float*)d_in[0];
    const float* x0  = (const float*)d_in[1];
    const float* U   = (const float*)d_in[2];
    const float* Wk  = (const float*)d_in[3];
    const float* bk  = (const float*)d_in[4];
    const float* Wad = (const float*)d_in[5];
    const float* bad = (const float*)d_in[6];
    const float* kg  = (const float*)d_in[7];
    const float* fg  = (const float*)d_in[8];
    const float* A1  = (const float*)d_in[9];
    const float* B1  = (const float*)d_in[10];
    const float* b1  = (const float*)d_in[11];
    const float* W2  = (const float*)d_in[12];
    const float* b2  = (const float*)d_in[13];
    float* out = (float*)d_out;

    unsigned char* ws = (unsigned char*)d_ws;
    const size_t offBase = 0;                       // base f32, 6291456 B
    const size_t offXC   = 6291456;                 // xc f32,   6291456 B
    const size_t offTF   = 12582912;                // tf16, 320 B (pad 1024)
    const size_t offB16  = 12583936;                // base16, 3145728 B
    const size_t offXF   = 15729664;                // xf16,   3145728 B
    const size_t offU16  = 18875392;                // 33554432 B
    const size_t offUT   = 52429824;                // 33554432 B
    const size_t needFast = 85984256;

    float* base = (float*)(ws + offBase);
    float* xc   = (float*)(ws + offXC);
    unsigned short* tf16 = (unsigned short*)(ws + offTF);

    const bool fast = (ws_size >= needFast);

    if (fast) {
        unsigned short* base16 = (unsigned short*)(ws + offB16);
        unsigned short* xf16   = (unsigned short*)(ws + offXF);
        unsigned short* U16    = (unsigned short*)(ws + offU16);
        unsigned short* UT16   = (unsigned short*)(ws + offUT);

        u_convert_kernel<<<dim3(64, 64), 256, 0, stream>>>(U, U16, UT16);
        base_pred_kernel<<<(BB * NN) / 256, 256, 0, stream>>>(
            hd, Wk, bk, Wad, bad, kg, base, base16);
        tfeat_kernel<<<1, 256, 0, stream>>>(tf16);
        // GEMM1: xc[row][m] = (1/64) * sum_k base16[row][k] * UT16[m][k]
        gemm_mfma<false><<<dim3(NN / 128, BLN / 128), 256, 0, stream>>>(
            base16, UT16, nullptr, xc, nullptr, 1.0f / 64.0f);
        // ODE: cond -> x_final (bf16, natural layout)
        ode_kernel<<<ELEMS / 128, 256, 0, stream>>>(
            x0, xc, tf16, A1, B1, b1, W2, b2, xf16);
        // GEMM2: out[row][m] = base + fg*64 * sum_k U16[m][k] * xf16[row][k]
        gemm_mfma<true><<<dim3(BLN / 128, NN / 128), 256, 0, stream>>>(
            U16, xf16, base, out, fg, 64.0f);
    } else {
        base_pred_kernel<<<(BB * NN) / 256, 256, 0, stream>>>(
            hd, Wk, bk, Wad, bad, kg, base, nullptr);
        tfeat_kernel<<<1, 256, 0, stream>>>(tf16);
        gemm_u<true><<<dim3(NN / GNT, BLN / GMT), 256, 0, stream>>>(
            base, U, nullptr, xc, nullptr, 1.0f / 64.0f);
        ode_kernel<<<ELEMS / 128, 256, 0, stream>>>(
            x0, xc, tf16, A1, B1, b1, W2, b2, nullptr);
        gemm_u<false><<<dim3(NN / GNT, BLN / GMT), 256, 0, stream>>>(
            xc, U, base, out, fg, 64.0f);
    }
}